// Round 11
// baseline (171.935 us; speedup 1.0000x reference)
//
#include <hip/hip_runtime.h>
#include <hip/hip_fp16.h>
#include <stdint.h>

#define NQ   300
#define CDIM 256
#define NH   8
#define HD   32
#define HWK  1024
#define HIDD 512

typedef __attribute__((ext_vector_type(8))) _Float16 f16x8;
typedef __attribute__((ext_vector_type(2))) _Float16 h2v;
typedef __attribute__((ext_vector_type(4))) float f32x4;

// ---- ws byte offsets ----
#define QB_OFF   0          // 300*256 f16 [q][c], scale folded
#define KB_OFF   153600     // 8*1024*32 f16 [h][k][d]
#define VT_OFF   677888     // [256 ch][1024 k] f16
#define PO_OFF   1202176    // [8 kr][300 q][256 c] f32 partial O
#define PL_OFF   3659776    // [8 kr][300 q][8 h] f32 partial exp-sums
#define A16_OFF  3736576    // [300][512] f16 a(q,f)
#define NX_OFF   4043776    // [512] f16 -wx
#define NY_OFF   4044800    // [512] f16 -wy
#define W2_OFF   4045824    // [8][512] f16 W2
#define QZ_OFF   4054016    // [300][8][16][32] f16 masked q-frag table (2.4 MB)

__device__ __forceinline__ short f16b(float x){
  _Float16 h = (_Float16)x;
  return __builtin_bit_cast(short, h);
}

__device__ __forceinline__ uint32_t pk_f16(float a, float b){
  auto r = __builtin_amdgcn_cvt_pkrtz(a, b);
  return __builtin_bit_cast(uint32_t, r);
}

__device__ __forceinline__ h2v cvt2h(float a, float b){
  auto r = __builtin_amdgcn_cvt_pkrtz(a, b);
  return __builtin_bit_cast(h2v, r);
}

// ---------------- launch 1: projections (quarter tiles) + prep tables ----------------
// bxid < 588: proj tiles (tile=bxid>>2, quarter=bxid&3); 16 rows x 64 cols.
//   tile<19: q->QB(+QZ diag); tile<83: k->KB [h][k][d]; else: v->VT transposed.
// bxid >= 588: prep work: a16, nx/ny, w216, qz zero-slots (disjoint from diag writes).
__global__ __launch_bounds__(256) void proj_kernel(
    const float* __restrict__ rq, const float* __restrict__ qp,
    const float* __restrict__ rs, const float* __restrict__ spe,
    const float* __restrict__ Wq, const float* __restrict__ bq,
    const float* __restrict__ Wk, const float* __restrict__ bk,
    const float* __restrict__ Wv, const float* __restrict__ bv,
    const float* __restrict__ refp, const float* __restrict__ W1,
    const float* __restrict__ b1, const float* __restrict__ W2,
    char* __restrict__ ws)
{
  int bxid = blockIdx.x;
  int tid = threadIdx.x;

  if (bxid >= 588){
    int pidx = (bxid - 588)*256 + tid;
    if (pidx < 153600){
      int q = pidx >> 9, f = pidx & 511;
      float2 w = ((const float2*)W1)[f];
      float a = fmaf(w.x, refp[2*q], fmaf(w.y, refp[2*q+1], b1[f]));
      ((short*)(ws + A16_OFF))[pidx] = f16b(a);
    } else if (pidx < 154112){
      int f = pidx - 153600;
      float2 w = ((const float2*)W1)[f];
      ((short*)(ws + NX_OFF))[f] = f16b(-w.x);
      ((short*)(ws + NY_OFF))[f] = f16b(-w.y);
    } else if (pidx < 158208){
      int e = pidx - 154112;
      ((short*)(ws + W2_OFF))[e] = f16b(W2[e]);
    } else if (pidx < 302208){
      int z = pidx - 158208;           // 144000 zero stores of 8 f16
      int g = z >> 2, p = z & 3;
      int q = g / 120, r = g - q*120;
      int h = r / 15,  m = r - h*15;
      int n = m + (m >= h ? 1 : 0);
      f16x8 z8 = {0,0,0,0,0,0,0,0};
      *(f16x8*)((short*)(ws + QZ_OFF) + (((q*NH + h)*16 + n) << 5) + p*8) = z8;
    }
    return;
  }

  int tile = bxid >> 2, quarter = bxid & 3;
  const float *in1, *in2, *W, *bias;
  int r0, M, mode;
  if (tile < 19){
    in1 = rq; in2 = qp; W = Wq; bias = bq; r0 = tile*16; M = NQ; mode = 0;
  } else if (tile < 83){
    in1 = rs; in2 = spe; W = Wk; bias = bk; r0 = (tile-19)*16; M = HWK; mode = 1;
  } else {
    in1 = rs; in2 = spe; W = Wv; bias = bv; r0 = (tile-83)*16; M = HWK; mode = 2;
  }
  __shared__ __align__(16) float At[32][20];
  __shared__ float Wl[32][68];
  int nq = tid & 63;
  int rg = tid >> 6;                 // rows rg*4 .. rg*4+3
  int n = quarter*64 + nq;
  float acc[4];
  float bv_ = bias[n];
  #pragma unroll
  for (int i=0;i<4;i++) acc[i] = bv_;

  for (int c0 = 0; c0 < CDIM; c0 += 32){
    __syncthreads();
    for (int e = tid; e < 512; e += 256){
      int r = e >> 5, c = e & 31;
      int gr = r0 + r; if (gr >= M) gr = M - 1;
      float v = in1[gr*CDIM + c0 + c];
      if (in2) v += in2[gr*CDIM + c0 + c];
      At[c][r] = v;
    }
    for (int e = tid; e < 2048; e += 256){
      int c = e & 31, nn = e >> 5;
      Wl[c][nn] = W[(quarter*64 + nn)*CDIM + c0 + c];
    }
    __syncthreads();
    #pragma unroll
    for (int c = 0; c < 32; c++){
      float w = Wl[c][nq];
      float4 a = *(const float4*)&At[c][rg*4];
      acc[0] = fmaf(a.x, w, acc[0]);
      acc[1] = fmaf(a.y, w, acc[1]);
      acc[2] = fmaf(a.z, w, acc[2]);
      acc[3] = fmaf(a.w, w, acc[3]);
    }
  }

  if (mode == 0){
    short* qb = (short*)(ws + QB_OFF);
    short* qz = (short*)(ws + QZ_OFF);
    const float s = 0.17677669529663687f;  // 1/sqrt(32)
    int h = n >> 5, d = n & 31;
    #pragma unroll
    for (int i=0;i<4;i++){
      int gr = r0 + rg*4 + i;
      if (gr < M){
        short v = f16b(acc[i]*s);
        qb[gr*CDIM + n] = v;
        qz[(((gr*NH + h)*16 + h) << 5) + d] = v;   // diagonal slot
      }
    }
  } else if (mode == 1){
    short* kb = (short*)(ws + KB_OFF);
    int h = n >> 5, d = n & 31;
    #pragma unroll
    for (int i=0;i<4;i++){
      int gr = r0 + rg*4 + i;
      if (gr < M) kb[((size_t)h*HWK + gr)*HD + d] = f16b(acc[i]);
    }
  } else {
    short* vt = (short*)(ws + VT_OFF);
    uint2 p2;
    p2.x = pk_f16(acc[0], acc[1]);
    p2.y = pk_f16(acc[2], acc[3]);
    *(uint2*)(vt + n*HWK + r0 + rg*4) = p2;
  }
}

// ---------------- fused: logits (qz-table MFMA) + CPB f16 + exp + partial PV ----------------
// grid = 2400: q = bid>>3, kr = bid&7 (128 k). 4 waves; wave owns one ky-row (32 k).
// No masked-frag registers: B-frags come straight from the qz table (8 x 1KB loads).
__global__ __launch_bounds__(256, 8) void fused_kernel(
    const short* __restrict__ a16, const short* __restrict__ nx16,
    const short* __restrict__ ny16, const short* __restrict__ w216,
    const short* __restrict__ qz, const short* __restrict__ kb,
    const short* __restrict__ vt, float* __restrict__ po,
    float* __restrict__ pl)
{
  int bid = blockIdx.x;
  int q = bid >> 3, kr = bid & 7;
  int tid = threadIdx.x, wave = tid >> 6, lane = tid & 63;
  int n = lane & 15, qd = lane >> 4;

  __shared__ __align__(16) _Float16 nwx[HIDD];      // -wx, 1KB
  __shared__ __align__(16) char pool[4096];         // c1s (phases 1-2) / part (phase 4)
  __shared__ __align__(16) _Float16 w2l[NH][520];   // W2 f16, 8.3KB
  __shared__ __align__(16) _Float16 pb[NH][136];    // 128 k exp, f16
  __shared__ float lsum[4][NH];
  _Float16 (*c1s)[HIDD] = (_Float16 (*)[HIDD])pool;
  float (*part)[NH][32] = (float (*)[NH][32])pool;

  // stage from f16 tables
  {
    int f0 = tid * 2;
    h2v a2  = *(const h2v*)(a16 + q*HIDD + f0);
    h2v ny2 = *(const h2v*)(ny16 + f0);
    h2v nx2 = *(const h2v*)(nx16 + f0);
    *(h2v*)&nwx[f0] = nx2;
    #pragma unroll
    for (int r = 0; r < 4; r++){
      _Float16 kyh = (_Float16)(((float)(kr*4 + r) + 0.5f) * (1.0f/32.0f));
      h2v ky2 = {kyh, kyh};
      *(h2v*)&c1s[r][f0] = ny2 * ky2 + a2;    // v_pk_fma_f16
    }
  }
  for (int e = tid; e < 512; e += 256){
    int r = e >> 6, c = e & 63;
    *(f16x8*)&w2l[r][c*8] = *(const f16x8*)(w216 + r*HIDD + c*8);
  }
  __syncthreads();

  const int kyrow = kr*4 + wave;          // global ky row (0..31)
  const int kbase = kyrow * 32;

  // ---- phase 1: logits -> acc registers, D[row=k-local][col=h] ----
  const short* qzq = qz + q*(NH*16*32);
  int loff = (n << 5) + qd*8;
  f32x4 acc[2] = {{0.f,0.f,0.f,0.f},{0.f,0.f,0.f,0.f}};
  #pragma unroll
  for (int h = 0; h < NH; h++){
    f16x8 bq_ = *(const f16x8*)(qzq + (h << 9) + loff);
    #pragma unroll
    for (int t = 0; t < 2; t++){
      int k0 = kbase + t*16;
      f16x8 af = *(const f16x8*)(kb + ((size_t)h*HWK + k0 + n)*HD + qd*8);
      acc[t] = __builtin_amdgcn_mfma_f32_16x16x32_f16(af, bq_, acc[t], 0, 0, 0);
    }
  }

  // ---- phase 2: acc += relu(c1 - wx*kx) @ W2^T, packed f16 ----
  _Float16 kxAh = (_Float16)(((float)n + 0.5f) * (1.0f/32.0f));
  _Float16 kxBh = (_Float16)(((float)n + 16.5f) * (1.0f/32.0f));
  f16x8 kxA8, kxB8, z8;
  #pragma unroll
  for (int j = 0; j < 8; j++){ kxA8[j] = kxAh; kxB8[j] = kxBh; z8[j] = (_Float16)0.f; }
  const _Float16* c1r = &c1s[wave][0];
  #pragma unroll 4
  for (int kc = 0; kc < 16; kc++){
    int f0 = kc*32 + qd*8;
    f16x8 c1v = *(const f16x8*)(c1r + f0);
    f16x8 wxv = *(const f16x8*)(&nwx[f0]);
    f16x8 bfr = *(const f16x8*)(&w2l[n & 7][f0]);
    #pragma unroll
    for (int t = 0; t < 2; t++){
      f16x8 kx8 = t ? kxB8 : kxA8;
      f16x8 e = __builtin_elementwise_max(wxv * kx8 + c1v, z8);
      acc[t] = __builtin_amdgcn_mfma_f32_16x16x32_f16(e, bfr, acc[t], 0, 0, 0);
    }
  }

  // ---- phase 3: exp (no max-subtract), pb f16, l partials ----
  float lacc = 0.f;
  #pragma unroll
  for (int t = 0; t < 2; t++){
    float e0 = __expf(acc[t][0]);
    float e1 = __expf(acc[t][1]);
    float e2 = __expf(acc[t][2]);
    float e3 = __expf(acc[t][3]);
    if (n < NH){
      uint2 p2;
      p2.x = pk_f16(e0, e1);
      p2.y = pk_f16(e2, e3);
      *(uint2*)&pb[n][wave*32 + t*16 + qd*4] = p2;
    }
    float s = e0 + e1 + e2 + e3;
    s += __shfl_xor(s, 16);
    s += __shfl_xor(s, 32);
    lacc += s;
  }
  if (lane < NH) lsum[wave][lane] = lacc;

  // ---- phase 4: partial PV over this wave's 32 k; part aliases c1s[wave] (own region) ----
  #pragma unroll
  for (int h = 0; h < NH; h++){
    int kl = wave*32 + qd*8;
    f16x8 pa = *(const f16x8*)&pb[h][kl];
    f16x8 v0 = *(const f16x8*)(vt + ((size_t)(h*HD +      n))*HWK + kr*128 + kl);
    f16x8 v1 = *(const f16x8*)(vt + ((size_t)(h*HD + 16 + n))*HWK + kr*128 + kl);
    f32x4 o0 = {0.f,0.f,0.f,0.f}, o1 = {0.f,0.f,0.f,0.f};
    o0 = __builtin_amdgcn_mfma_f32_16x16x32_f16(pa, v0, o0, 0, 0, 0);
    o1 = __builtin_amdgcn_mfma_f32_16x16x32_f16(pa, v1, o1, 0, 0, 0);
    if (qd == 0){
      part[wave][h][n]      = o0[0];
      part[wave][h][16 + n] = o1[0];
    }
  }
  __syncthreads();

  // ---- combine waves, write partials ----
  {
    int h = tid >> 5, d = tid & 31;
    float s = part[0][h][d] + part[1][h][d] + part[2][h][d] + part[3][h][d];
    po[((size_t)kr*NQ + q)*CDIM + tid] = s;
    if (tid < NH)
      pl[((size_t)kr*NQ + q)*NH + tid] =
          lsum[0][tid] + lsum[1][tid] + lsum[2][tid] + lsum[3][tid];
  }
}

// ---------------- final projection: gather 8 PV partials, normalize, GEMM with Wo ----------------
__global__ __launch_bounds__(256) void projf_kernel(
    const float* __restrict__ Wo, const float* __restrict__ bo,
    char* __restrict__ ws, float* __restrict__ dout)
{
  int bxid = blockIdx.x;
  int tile = bxid >> 1, half = bxid & 1;
  const float* po = (const float*)(ws + PO_OFF);
  const float* pl = (const float*)(ws + PL_OFF);
  int r0 = tile*16, M = NQ;
  __shared__ __align__(16) float At[32][20];
  __shared__ float Wl[32][129];
  __shared__ float linv[16][8];
  int tid = threadIdx.x;
  int n_loc = tid & 127;
  int rg = tid >> 7;
  int n = half*128 + n_loc;
  float acc[8];
  float bv_ = bo[n];
  #pragma unroll
  for (int i=0;i<8;i++) acc[i] = bv_;

  if (tid < 128){
    int r = tid >> 3, hh = tid & 7;
    int gr = r0 + r; if (gr >= M) gr = M - 1;
    float s = 0.f;
    #pragma unroll
    for (int p = 0; p < 8; p++) s += pl[((size_t)p*NQ+gr)*NH+hh];
    linv[r][hh] = 1.0f / s;
  }

  for (int c0 = 0; c0 < CDIM; c0 += 32){
    __syncthreads();
    for (int e = tid; e < 512; e += 256){
      int r = e >> 5, c = e & 31;
      int gr = r0 + r; if (gr >= M) gr = M - 1;
      int cc = c0 + c;
      float v = 0.f;
      #pragma unroll
      for (int p = 0; p < 8; p++) v += po[(size_t)(p*NQ+gr)*CDIM + cc];
      At[c][r] = v * linv[r][c0 >> 5];
    }
    for (int e = tid; e < 4096; e += 256){
      int c = e & 31, nn = e >> 5;
      Wl[c][nn] = Wo[(half*128 + nn)*CDIM + c0 + c];
    }
    __syncthreads();
    #pragma unroll
    for (int c = 0; c < 32; c++){
      float w = Wl[c][n_loc];
      const float4* ap = (const float4*)&At[c][rg*8];
      float4 a0 = ap[0], a1 = ap[1];
      acc[0] = fmaf(a0.x, w, acc[0]);
      acc[1] = fmaf(a0.y, w, acc[1]);
      acc[2] = fmaf(a0.z, w, acc[2]);
      acc[3] = fmaf(a0.w, w, acc[3]);
      acc[4] = fmaf(a1.x, w, acc[4]);
      acc[5] = fmaf(a1.y, w, acc[5]);
      acc[6] = fmaf(a1.z, w, acc[6]);
      acc[7] = fmaf(a1.w, w, acc[7]);
    }
  }
  #pragma unroll
  for (int i=0;i<8;i++){
    int gr = r0 + rg*8 + i;
    if (gr < M) dout[gr*CDIM + n] = acc[i];
  }
}

extern "C" void kernel_launch(void* const* d_in, const int* in_sizes, int n_in,
                              void* d_out, int out_size, void* d_ws, size_t ws_size,
                              hipStream_t stream)
{
  const float* rq  = (const float*)d_in[0];
  const float* qp  = (const float*)d_in[1];
  const float* rp  = (const float*)d_in[2];
  const float* rs  = (const float*)d_in[3];
  const float* spe = (const float*)d_in[4];
  const float* Wq  = (const float*)d_in[5];
  const float* bq  = (const float*)d_in[6];
  const float* Wk  = (const float*)d_in[7];
  const float* bk  = (const float*)d_in[8];
  const float* Wv  = (const float*)d_in[9];
  const float* bv  = (const float*)d_in[10];
  const float* Wo  = (const float*)d_in[11];
  const float* bo  = (const float*)d_in[12];
  const float* W1  = (const float*)d_in[13];
  const float* b1  = (const float*)d_in[14];
  const float* W2  = (const float*)d_in[15];
  char* ws = (char*)d_ws;
  float* dout = (float*)d_out;

  proj_kernel<<<1769, 256, 0, stream>>>(rq, qp, rs, spe, Wq, bq, Wk, bk,
      Wv, bv, rp, W1, b1, W2, ws);
  fused_kernel<<<2400, 256, 0, stream>>>((const short*)(ws + A16_OFF),
      (const short*)(ws + NX_OFF), (const short*)(ws + NY_OFF),
      (const short*)(ws + W2_OFF), (const short*)(ws + QZ_OFF),
      (const short*)(ws + KB_OFF), (const short*)(ws + VT_OFF),
      (float*)(ws + PO_OFF), (float*)(ws + PL_OFF));
  projf_kernel<<<38, 256, 0, stream>>>(Wo, bo, ws, dout);
}

// Round 12
// 154.520 us; speedup vs baseline: 1.1127x; 1.1127x over previous
//
#include <hip/hip_runtime.h>
#include <hip/hip_fp16.h>
#include <stdint.h>

#define NQ   300
#define CDIM 256
#define NH   8
#define HD   32
#define HWK  1024
#define HIDD 512

typedef __attribute__((ext_vector_type(8))) _Float16 f16x8;
typedef __attribute__((ext_vector_type(2))) _Float16 h2v;
typedef __attribute__((ext_vector_type(4))) float f32x4;

// ---- ws byte offsets ----
#define QB_OFF   0          // 300*256 f16 [q][c], scale folded
#define KB_OFF   153600     // 8*1024*32 f16 [h][k][d]
#define VT_OFF   677888     // [256 ch][1024 k] f16
#define PO_OFF   1202176    // [8 kr][300 q][256 c] f32 partial O
#define PL_OFF   3659776    // [8 kr][300 q][8 h] f32 partial exp-sums
#define A16_OFF  3736576    // [300][512] f16 a(q,f)
#define NX_OFF   4043776    // [512] f16 -wx
#define NY_OFF   4044800    // [512] f16 -wy
#define W2_OFF   4045824    // [8][512] f16 W2

__device__ __forceinline__ short f16b(float x){
  _Float16 h = (_Float16)x;
  return __builtin_bit_cast(short, h);
}

__device__ __forceinline__ uint32_t pk_f16(float a, float b){
  auto r = __builtin_amdgcn_cvt_pkrtz(a, b);
  return __builtin_bit_cast(uint32_t, r);
}

__device__ __forceinline__ h2v cvt2h(float a, float b){
  auto r = __builtin_amdgcn_cvt_pkrtz(a, b);
  return __builtin_bit_cast(h2v, r);
}

// ---------------- prep: f16 tables ----------------
__global__ __launch_bounds__(256) void prep_kernel(
    const float* __restrict__ refp, const float* __restrict__ W1,
    const float* __restrict__ b1, const float* __restrict__ W2,
    short* __restrict__ a16, short* __restrict__ nx16,
    short* __restrict__ ny16, short* __restrict__ w216)
{
  int idx = blockIdx.x * 256 + threadIdx.x;
  if (idx < NQ*HIDD){
    int q = idx >> 9, f = idx & 511;
    float2 w = ((const float2*)W1)[f];
    float a = fmaf(w.x, refp[2*q], fmaf(w.y, refp[2*q+1], b1[f]));
    a16[idx] = f16b(a);
  } else {
    int j = idx - NQ*HIDD;
    if (j < HIDD){
      float2 w = ((const float2*)W1)[j];
      nx16[j] = f16b(-w.x);
      ny16[j] = f16b(-w.y);
    } else if (j < HIDD + NH*HIDD){
      int e = j - HIDD;
      w216[e] = f16b(W2[e]);
    }
  }
}

// ---------------- generic projection GEMM ----------------
// mode 0: q -> QB f16 (scaled); 1: k -> KB [h][k][d]; 2: v -> VT transposed;
// mode 3 (final): A = sum of 8 PV partials * 1/sum(l), GEMM with Wo -> d_out
__global__ __launch_bounds__(256) void proj_kernel(
    const float* __restrict__ rq, const float* __restrict__ qp,
    const float* __restrict__ rs, const float* __restrict__ spe,
    const float* __restrict__ Wq, const float* __restrict__ bq,
    const float* __restrict__ Wk, const float* __restrict__ bk,
    const float* __restrict__ Wv, const float* __restrict__ bv,
    const float* __restrict__ Wo, const float* __restrict__ bo,
    char* __restrict__ ws, float* __restrict__ dout, int final_mode)
{
  int bxid = blockIdx.x;
  int tile = bxid >> 1, half = bxid & 1;
  const float *in1, *in2, *W, *bias;
  int r0, M, mode;
  const float* po = (const float*)(ws + PO_OFF);
  const float* pl = (const float*)(ws + PL_OFF);
  if (final_mode){
    in1 = po; in2 = nullptr; W = Wo; bias = bo;
    r0 = tile*16; M = NQ; mode = 3;
  } else if (tile < 19){
    in1 = rq; in2 = qp; W = Wq; bias = bq; r0 = tile*16; M = NQ; mode = 0;
  } else if (tile < 83){
    in1 = rs; in2 = spe; W = Wk; bias = bk; r0 = (tile-19)*16; M = HWK; mode = 1;
  } else {
    in1 = rs; in2 = spe; W = Wv; bias = bv; r0 = (tile-83)*16; M = HWK; mode = 2;
  }
  __shared__ __align__(16) float At[32][20];
  __shared__ float Wl[32][129];
  __shared__ float linv[16][8];
  int tid = threadIdx.x;
  int n_loc = tid & 127;
  int rg = tid >> 7;
  int n = half*128 + n_loc;
  float acc[8];
  float bv_ = bias[n];
  #pragma unroll
  for (int i=0;i<8;i++) acc[i] = bv_;

  if (mode == 3 && tid < 128){
    int r = tid >> 3, hh = tid & 7;
    int gr = r0 + r; if (gr >= M) gr = M - 1;
    float s = 0.f;
    #pragma unroll
    for (int p = 0; p < 8; p++) s += pl[((size_t)p*NQ+gr)*NH+hh];
    linv[r][hh] = 1.0f / s;
  }

  for (int c0 = 0; c0 < CDIM; c0 += 32){
    __syncthreads();
    for (int e = tid; e < 512; e += 256){
      int r = e >> 5, c = e & 31;
      int gr = r0 + r; if (gr >= M) gr = M - 1;
      float v;
      if (mode == 3){
        int cc = c0 + c;
        v = 0.f;
        #pragma unroll
        for (int p = 0; p < 8; p++) v += po[(size_t)(p*NQ+gr)*CDIM + cc];
        v *= linv[r][c0 >> 5];
      } else {
        v = in1[gr*CDIM + c0 + c];
        if (in2) v += in2[gr*CDIM + c0 + c];
      }
      At[c][r] = v;
    }
    for (int e = tid; e < 4096; e += 256){
      int c = e & 31, nn = e >> 5;
      Wl[c][nn] = W[(half*128 + nn)*CDIM + c0 + c];
    }
    __syncthreads();
    #pragma unroll
    for (int c = 0; c < 32; c++){
      float w = Wl[c][n_loc];
      const float4* ap = (const float4*)&At[c][rg*8];
      float4 a0 = ap[0], a1 = ap[1];
      acc[0] = fmaf(a0.x, w, acc[0]);
      acc[1] = fmaf(a0.y, w, acc[1]);
      acc[2] = fmaf(a0.z, w, acc[2]);
      acc[3] = fmaf(a0.w, w, acc[3]);
      acc[4] = fmaf(a1.x, w, acc[4]);
      acc[5] = fmaf(a1.y, w, acc[5]);
      acc[6] = fmaf(a1.z, w, acc[6]);
      acc[7] = fmaf(a1.w, w, acc[7]);
    }
  }

  if (mode == 0){
    short* qb = (short*)(ws + QB_OFF);
    const float s = 0.17677669529663687f;  // 1/sqrt(32)
    #pragma unroll
    for (int i=0;i<8;i++){
      int gr = r0 + rg*8 + i;
      if (gr < M) qb[gr*CDIM + n] = f16b(acc[i]*s);
    }
  } else if (mode == 1){
    short* kb = (short*)(ws + KB_OFF);
    int h = n >> 5, d = n & 31;
    #pragma unroll
    for (int i=0;i<8;i++){
      int gr = r0 + rg*8 + i;
      if (gr < M) kb[((size_t)h*HWK + gr)*HD + d] = f16b(acc[i]);
    }
  } else if (mode == 2){
    short* vt = (short*)(ws + VT_OFF);
    uint32_t p[4];
    #pragma unroll
    for (int i=0;i<4;i++) p[i] = pk_f16(acc[2*i], acc[2*i+1]);
    *(uint4*)(vt + n*HWK + r0 + rg*8) = make_uint4(p[0], p[1], p[2], p[3]);
  } else {
    #pragma unroll
    for (int i=0;i<8;i++){
      int gr = r0 + rg*8 + i;
      if (gr < M) dout[gr*CDIM + n] = acc[i];
    }
  }
}

// ---------------- fused: 2 queries/block, logits + CPB f16 + exp + partial PV ----------------
// grid = 1200: qpair = bid>>3 (q0=2*qpair), kr = bid&7 (128 k). 4 waves; wave owns one ky-row.
// Phase-1 B cols 0-7 = q0 heads, 8-15 = q1 heads (masked regs, 2 cols/MFMA).
// Phase-2: 4 independent chains (2q x 2t), seeded from the shared phase-1 D.
__global__ __launch_bounds__(256, 4) void fused_kernel(
    const short* __restrict__ a16, const short* __restrict__ nx16,
    const short* __restrict__ ny16, const short* __restrict__ w216,
    const short* __restrict__ qb, const short* __restrict__ kb,
    const short* __restrict__ vt, float* __restrict__ po,
    float* __restrict__ pl)
{
  int bid = blockIdx.x;
  int q0 = (bid >> 3) * 2, kr = bid & 7;
  int tid = threadIdx.x, wave = tid >> 6, lane = tid & 63;
  int n = lane & 15, qd = lane >> 4;

  __shared__ __align__(16) _Float16 nwx[HIDD];      // 1KB
  __shared__ __align__(16) char pool[8192];         // c1s (ph1-2) / part (ph4), per-wave regions
  __shared__ __align__(16) _Float16 w2l[NH][520];   // 8.3KB
  __shared__ __align__(16) _Float16 pb[2][NH][136]; // 4.3KB
  __shared__ float lsum[4][16];
  _Float16 (*c1s)[4][HIDD] = (_Float16 (*)[4][HIDD])pool;  // [qq][kyrow-local][f]
  float (*part)[4][NH][32] = (float (*)[4][NH][32])pool;   // [qq][wave][h][d] — same region map

  // ---- staging from f16 tables ----
  {
    int f0 = tid * 2;
    h2v ny2 = *(const h2v*)(ny16 + f0);
    h2v nx2 = *(const h2v*)(nx16 + f0);
    *(h2v*)&nwx[f0] = nx2;
    #pragma unroll
    for (int qq = 0; qq < 2; qq++){
      h2v a2 = *(const h2v*)(a16 + (q0+qq)*HIDD + f0);
      #pragma unroll
      for (int r = 0; r < 4; r++){
        _Float16 kyh = (_Float16)(((float)(kr*4 + r) + 0.5f) * (1.0f/32.0f));
        h2v ky2 = {kyh, kyh};
        *(h2v*)&c1s[qq][r][f0] = ny2 * ky2 + a2;    // v_pk_fma_f16
      }
    }
  }
  for (int e = tid; e < 512; e += 256){
    int r = e >> 6, c = e & 63;
    *(f16x8*)&w2l[r][c*8] = *(const f16x8*)(w216 + r*HIDD + c*8);
  }
  // masked q fragments: col n = query (n>>3), head (n&7)
  f16x8 qfrag = *(const f16x8*)(qb + (q0 + (n >> 3))*CDIM + (n & 7)*HD + qd*8);
  f16x8 qm[NH];
  #pragma unroll
  for (int h = 0; h < NH; h++){
    f16x8 z = {0,0,0,0,0,0,0,0};
    qm[h] = ((n & 7) == h) ? qfrag : z;
  }
  __syncthreads();

  const int kyrow = kr*4 + wave;          // global ky row (0..31)
  const int kbase = kyrow * 32;

  // ---- phase 1: logits for both queries -> acc1, D[row=k-local][col: 0-7 q0, 8-15 q1] ----
  f32x4 acc1[2] = {{0.f,0.f,0.f,0.f},{0.f,0.f,0.f,0.f}};
  #pragma unroll
  for (int t = 0; t < 2; t++){
    int k0 = kbase + t*16;
    #pragma unroll
    for (int h = 0; h < NH; h++){
      f16x8 af = *(const f16x8*)(kb + ((size_t)h*HWK + k0 + n)*HD + qd*8);
      acc1[t] = __builtin_amdgcn_mfma_f32_16x16x32_f16(af, qm[h], acc1[t], 0, 0, 0);
    }
  }

  // ---- phase 2: 4 chains accb[qq][t] += relu(c1_qq - wx*kx) @ W2^T ----
  _Float16 kxAh = (_Float16)(((float)n + 0.5f) * (1.0f/32.0f));
  _Float16 kxBh = (_Float16)(((float)n + 16.5f) * (1.0f/32.0f));
  f16x8 kxA8, kxB8, z8;
  #pragma unroll
  for (int j = 0; j < 8; j++){ kxA8[j] = kxAh; kxB8[j] = kxBh; z8[j] = (_Float16)0.f; }
  f32x4 accb[2][2];
  accb[0][0] = acc1[0]; accb[0][1] = acc1[1];
  accb[1][0] = acc1[0]; accb[1][1] = acc1[1];
  const _Float16* c1r0 = &c1s[0][wave][0];
  const _Float16* c1r1 = &c1s[1][wave][0];
  #pragma unroll 4
  for (int kc = 0; kc < 16; kc++){
    int f0 = kc*32 + qd*8;
    f16x8 c10 = *(const f16x8*)(c1r0 + f0);
    f16x8 c11 = *(const f16x8*)(c1r1 + f0);
    f16x8 wxv = *(const f16x8*)(&nwx[f0]);
    f16x8 bfr = *(const f16x8*)(&w2l[n & 7][f0]);
    #pragma unroll
    for (int t = 0; t < 2; t++){
      f16x8 kx8 = t ? kxB8 : kxA8;
      f16x8 e0 = __builtin_elementwise_max(wxv * kx8 + c10, z8);
      accb[0][t] = __builtin_amdgcn_mfma_f32_16x16x32_f16(e0, bfr, accb[0][t], 0, 0, 0);
      f16x8 e1 = __builtin_elementwise_max(wxv * kx8 + c11, z8);
      accb[1][t] = __builtin_amdgcn_mfma_f32_16x16x32_f16(e1, bfr, accb[1][t], 0, 0, 0);
    }
  }

  // ---- phase 3: exp (no max-subtract), pb f16, l partials; lane's query = n>>3 ----
  int qsel = n >> 3, hsel = n & 7;
  float lacc = 0.f;
  #pragma unroll
  for (int t = 0; t < 2; t++){
    f32x4 a = qsel ? accb[1][t] : accb[0][t];
    float e0 = __expf(a[0]);
    float e1 = __expf(a[1]);
    float e2 = __expf(a[2]);
    float e3 = __expf(a[3]);
    uint2 p2;
    p2.x = pk_f16(e0, e1);
    p2.y = pk_f16(e2, e3);
    *(uint2*)&pb[qsel][hsel][wave*32 + t*16 + qd*4] = p2;
    float s = e0 + e1 + e2 + e3;
    s += __shfl_xor(s, 16);
    s += __shfl_xor(s, 32);
    lacc += s;
  }
  if (lane < 16) lsum[wave][lane] = lacc;

  // ---- phase 4: PV for both queries (A row 0 = q0 p, row 1 = q1 p) ----
  // part aliases this wave's own dead c1s regions (c1s[qq][wave] == part[qq][wave]).
  #pragma unroll
  for (int h = 0; h < NH; h++){
    int kl = wave*32 + qd*8;
    f16x8 pa = *(const f16x8*)&pb[n & 1][h][kl];
    f16x8 v0 = *(const f16x8*)(vt + ((size_t)(h*HD +      n))*HWK + kr*128 + kl);
    f16x8 v1 = *(const f16x8*)(vt + ((size_t)(h*HD + 16 + n))*HWK + kr*128 + kl);
    f32x4 o0 = {0.f,0.f,0.f,0.f}, o1 = {0.f,0.f,0.f,0.f};
    o0 = __builtin_amdgcn_mfma_f32_16x16x32_f16(pa, v0, o0, 0, 0, 0);
    o1 = __builtin_amdgcn_mfma_f32_16x16x32_f16(pa, v1, o1, 0, 0, 0);
    if (qd == 0){
      part[0][wave][h][n]      = o0[0];   // D row 0 = q0
      part[1][wave][h][n]      = o0[1];   // D row 1 = q1
      part[0][wave][h][16 + n] = o1[0];
      part[1][wave][h][16 + n] = o1[1];
    }
  }
  __syncthreads();

  // ---- combine waves, write partials for both queries ----
  {
    int h = tid >> 5, d = tid & 31;
    #pragma unroll
    for (int qq = 0; qq < 2; qq++){
      float s = part[qq][0][h][d] + part[qq][1][h][d]
              + part[qq][2][h][d] + part[qq][3][h][d];
      po[((size_t)kr*NQ + q0 + qq)*CDIM + tid] = s;
    }
    if (tid < 16){
      float s = lsum[0][tid] + lsum[1][tid] + lsum[2][tid] + lsum[3][tid];
      pl[((size_t)kr*NQ + q0 + (tid >> 3))*NH + (tid & 7)] = s;
    }
  }
}

extern "C" void kernel_launch(void* const* d_in, const int* in_sizes, int n_in,
                              void* d_out, int out_size, void* d_ws, size_t ws_size,
                              hipStream_t stream)
{
  const float* rq  = (const float*)d_in[0];
  const float* qp  = (const float*)d_in[1];
  const float* rp  = (const float*)d_in[2];
  const float* rs  = (const float*)d_in[3];
  const float* spe = (const float*)d_in[4];
  const float* Wq  = (const float*)d_in[5];
  const float* bq  = (const float*)d_in[6];
  const float* Wk  = (const float*)d_in[7];
  const float* bk  = (const float*)d_in[8];
  const float* Wv  = (const float*)d_in[9];
  const float* bv  = (const float*)d_in[10];
  const float* Wo  = (const float*)d_in[11];
  const float* bo  = (const float*)d_in[12];
  const float* W1  = (const float*)d_in[13];
  const float* b1  = (const float*)d_in[14];
  const float* W2  = (const float*)d_in[15];
  char* ws = (char*)d_ws;
  float* dout = (float*)d_out;

  prep_kernel<<<618, 256, 0, stream>>>(rp, W1, b1, W2,
      (short*)(ws + A16_OFF), (short*)(ws + NX_OFF),
      (short*)(ws + NY_OFF), (short*)(ws + W2_OFF));
  proj_kernel<<<294, 256, 0, stream>>>(rq, qp, rs, spe, Wq, bq, Wk, bk,
      Wv, bv, Wo, bo, ws, dout, 0);
  fused_kernel<<<1200, 256, 0, stream>>>((const short*)(ws + A16_OFF),
      (const short*)(ws + NX_OFF), (const short*)(ws + NY_OFF),
      (const short*)(ws + W2_OFF), (const short*)(ws + QB_OFF),
      (const short*)(ws + KB_OFF), (const short*)(ws + VT_OFF),
      (float*)(ws + PO_OFF), (float*)(ws + PL_OFF));
  proj_kernel<<<38, 256, 0, stream>>>(rq, qp, rs, spe, Wq, bq, Wk, bk,
      Wv, bv, Wo, bo, ws, dout, 1);
}